// Round 5
// baseline (633.447 us; speedup 1.0000x reference)
//
#include <hip/hip_runtime.h>
#include <hip/hip_bf16.h>

// BitNet b1.58 linear: out = scale * (x @ clip(round(w/scale),-1,1)^T)
// scale = 1e-4 + mean(|w|).  M=8192, N=8192, K=2048, fp32 in/out.
// Pipeline: deterministic 2-stage |w| reduction (scratch in d_out tail) ->
// prep (q = bf16 {-1,0,1}, xs = bf16(x*scale)) ->
// 256x256 8-phase bf16 MFMA GEMM (T2 swizzle + T3/T4 counted vmcnt + T5 setprio)
// with >=2-phase staging slack and a coalesced float4 epilogue via LDS.

typedef __bf16 bf16x8 __attribute__((ext_vector_type(8)));
typedef float  f32x4  __attribute__((ext_vector_type(4)));

#define GAS __attribute__((address_space(1)))
#define LAS __attribute__((address_space(3)))

static constexpr int  M_DIM = 8192;
static constexpr int  N_DIM = 8192;
static constexpr int  K_DIM = 2048;
static constexpr long NELEM = 16777216;

// --------------------------------------------- stage 1: per-block |w| sums
__global__ void absmean1_kernel(const float* __restrict__ w, double* __restrict__ partials) {
    double s = 0.0;
    const float4* w4 = (const float4*)w;
    const int n4 = (int)(NELEM / 4);
    for (int i = blockIdx.x * blockDim.x + threadIdx.x; i < n4; i += gridDim.x * blockDim.x) {
        float4 v = w4[i];
        s += (double)fabsf(v.x) + (double)fabsf(v.y) + (double)fabsf(v.z) + (double)fabsf(v.w);
    }
    #pragma unroll
    for (int off = 32; off > 0; off >>= 1) s += __shfl_down(s, off);
    __shared__ double wsum[4];
    if ((threadIdx.x & 63) == 0) wsum[threadIdx.x >> 6] = s;
    __syncthreads();
    if (threadIdx.x == 0) partials[blockIdx.x] = wsum[0] + wsum[1] + wsum[2] + wsum[3];
}

// --------------------------------------------- stage 2: partials -> scale
__global__ void absmean2_kernel(const double* __restrict__ partials, float* __restrict__ scale_out) {
    double s = 0.0;
    #pragma unroll
    for (int j = 0; j < 8; ++j) s += partials[threadIdx.x + 256 * j];
    #pragma unroll
    for (int off = 32; off > 0; off >>= 1) s += __shfl_down(s, off);
    __shared__ double wsum[4];
    if ((threadIdx.x & 63) == 0) wsum[threadIdx.x >> 6] = s;
    __syncthreads();
    if (threadIdx.x == 0) {
        double total = wsum[0] + wsum[1] + wsum[2] + wsum[3];
        scale_out[0] = (float)(1.0e-4 + total * (1.0 / 16777216.0));
    }
}

// ----------------------------- prep: qw = quantized w (bf16), xs = bf16(x*scale)
__global__ void prep_kernel(const float* __restrict__ x, const float* __restrict__ w,
                            const float* __restrict__ scale_in,
                            __bf16* __restrict__ xs, __bf16* __restrict__ qw) {
    const float scale = scale_in[0];
    const int n8 = (int)(NELEM / 8);
    const float4* x4 = (const float4*)x;
    const float4* w4 = (const float4*)w;
    for (int i = blockIdx.x * blockDim.x + threadIdx.x; i < n8; i += gridDim.x * blockDim.x) {
        float4 a0 = x4[2 * i], a1 = x4[2 * i + 1];
        bf16x8 xv;
        xv[0] = (__bf16)(a0.x * scale); xv[1] = (__bf16)(a0.y * scale);
        xv[2] = (__bf16)(a0.z * scale); xv[3] = (__bf16)(a0.w * scale);
        xv[4] = (__bf16)(a1.x * scale); xv[5] = (__bf16)(a1.y * scale);
        xv[6] = (__bf16)(a1.z * scale); xv[7] = (__bf16)(a1.w * scale);
        *(bf16x8*)(xs + 8l * i) = xv;

        float4 b0 = w4[2 * i], b1 = w4[2 * i + 1];
        float wv[8] = {b0.x, b0.y, b0.z, b0.w, b1.x, b1.y, b1.z, b1.w};
        bf16x8 qv;
        #pragma unroll
        for (int e = 0; e < 8; ++e) {
            float r = rintf(wv[e] / scale);
            r = fminf(1.0f, fmaxf(-1.0f, r));
            qv[e] = (__bf16)r;
        }
        *(bf16x8*)(qw + 8l * i) = qv;
    }
}

// ------------------------------------------------------------------ GEMM
// C[m][n] = sum_k A[m][k]*B[n][k].  256x256 tile, BK=64, 512 thr = 8 waves (2Mx4N).
// LDS 128KiB: [dbuf 2][A/B][256 rows][64 cols] bf16, 16B chunks permuted chunk^(row&7)
// (linear dest for global_load_lds, pre-swizzled global source, swizzled ds_read).
// Staging schedule (granule -> stage phase -> drain wait; >=2-phase slack each):
//   q0: d1.B.h0(kt1)            drained q3   (3 ph)
//   q1: d1.B.h1(kt1)            drained q3   (2 ph)
//   q2: d1.A.t1(kt1)            drained q4   (2 ph; first READ at q5, mq=1)
//   q3: d0.A.t0(kt2) + vmcnt(4)  drained q7   (4 ph)
//   q4: d0.B.h0(kt2)+d0.A.t1(kt2) + vmcnt(6)  drained q7 (3 ph)
//   q5: d0.B.h1(kt2)            drained q7   (2 ph)
//   q6: (none)
//   q7: d1.A.t0(kt3) + vmcnt(2)  drained next q3 (4 ph)
// WAR: each granule staged only after its last-reader phase's closing barrier.

#define STAGE_A(dd, t, kt) do { \
    _Pragma("unroll") for (int _h = 0; _h < 2; ++_h) { \
        const __bf16* _g = A + (long)(bm * 256 + _h * 128 + (t) * 64 + (tid >> 3)) * K_DIM \
                             + (kt) * 64 + schunk * 8; \
        __builtin_amdgcn_global_load_lds((const GAS unsigned int*)_g, \
            (LAS unsigned int*)(lds + (dd) * 32768 + _h * 8192 + (t) * 4096 + wid * 512), 16, 0, 0); \
    } } while (0)

#define STAGE_B(dd, h, kt) do { \
    _Pragma("unroll") for (int _t = 0; _t < 2; ++_t) { \
        const __bf16* _g = B + (long)(bn * 256 + (h) * 128 + _t * 64 + (tid >> 3)) * K_DIM \
                             + (kt) * 64 + schunk * 8; \
        __builtin_amdgcn_global_load_lds((const GAS unsigned int*)_g, \
            (LAS unsigned int*)(lds + (dd) * 32768 + 16384 + (h) * 8192 + _t * 4096 + wid * 512), 16, 0, 0); \
    } } while (0)

#define VM2 asm volatile("s_waitcnt vmcnt(2)" ::: "memory")
#define VM4 asm volatile("s_waitcnt vmcnt(4)" ::: "memory")
#define VM6 asm volatile("s_waitcnt vmcnt(6)" ::: "memory")

#define PHASE(dd, mq, nq, STG, DOVM) do { \
    bf16x8 af[4][2], bg[2][2]; \
    _Pragma("unroll") for (int mi = 0; mi < 4; ++mi) \
        _Pragma("unroll") for (int kk = 0; kk < 2; ++kk) \
            af[mi][kk] = *(const bf16x8*)(L + (dd) * 65536 \
                + (wr * 128 + (mq) * 64 + mi * 16 + l15) * 128 + (kk ? kb1 : kb0)); \
    _Pragma("unroll") for (int nj = 0; nj < 2; ++nj) \
        _Pragma("unroll") for (int kk = 0; kk < 2; ++kk) \
            bg[nj][kk] = *(const bf16x8*)(L + (dd) * 65536 + 32768 \
                + (wc * 64 + (nq) * 32 + nj * 16 + l15) * 128 + (kk ? kb1 : kb0)); \
    STG; \
    __builtin_amdgcn_s_barrier(); \
    asm volatile("s_waitcnt lgkmcnt(0)" ::: "memory"); \
    __builtin_amdgcn_sched_barrier(0); \
    __builtin_amdgcn_s_setprio(1); \
    _Pragma("unroll") for (int mi = 0; mi < 4; ++mi) \
        _Pragma("unroll") for (int nj = 0; nj < 2; ++nj) \
            _Pragma("unroll") for (int kk = 0; kk < 2; ++kk) \
                acc[(mq) * 4 + mi][(nq) * 2 + nj] = __builtin_amdgcn_mfma_f32_16x16x32_bf16( \
                    af[mi][kk], bg[nj][kk], acc[(mq) * 4 + mi][(nq) * 2 + nj], 0, 0, 0); \
    __builtin_amdgcn_s_setprio(0); \
    DOVM; \
    __builtin_amdgcn_s_barrier(); \
} while (0)

__global__ __launch_bounds__(512, 2) void gemm_kernel(const __bf16* __restrict__ A,
                                                      const __bf16* __restrict__ B,
                                                      float* __restrict__ C) {
    __shared__ __bf16 lds[65536];   // 128 KiB: [d][A/B][256][64]; reused fp32 in epilogue

    const int tid  = threadIdx.x;
    const int lane = tid & 63;
    const int wid  = tid >> 6;       // 0..7
    const int wr   = wid >> 2;       // 0..1 -> M half (128 rows)
    const int wc   = wid & 3;        // 0..3 -> N quarter (64 cols)
    const int l15  = lane & 15;

    // XCD-aware bijective swizzle (nwg = 1024, %8 == 0)
    const int linear = blockIdx.y * gridDim.x + blockIdx.x;
    const int swzid  = (linear & 7) * 128 + (linear >> 3);
    const int bm = swzid >> 5;       // 0..31
    const int bn = swzid & 31;       // 0..31

    // staging: lane covers LDS row tid>>3, chunk tid&7 of an 8KB inst-region;
    // global source chunk pre-swizzled so LDS[row][c] = G[row][c^(row&7)]
    const int schunk = (tid & 7) ^ ((tid >> 3) & 7);

    // fragment-read byte offsets within a 128B row (matching swizzle)
    const int swz = (lane & 7) << 4;
    const int khi = ((lane >> 4) & 3) << 4;
    const int kb0 = khi ^ swz;
    const int kb1 = (khi | 64) ^ swz;
    const char* L = (const char*)lds;

    f32x4 acc[8][4];
    #pragma unroll
    for (int i = 0; i < 8; ++i)
        #pragma unroll
        for (int j = 0; j < 4; ++j)
            acc[i][j] = f32x4{0.0f, 0.0f, 0.0f, 0.0f};

    // prologue: tile0 -> dbuf0 (8 loads), d1.A.t0(kt1) (2 loads); drain tile0
    STAGE_A(0, 0, 0);
    STAGE_A(0, 1, 0);
    STAGE_B(0, 0, 0);
    STAGE_B(0, 1, 0);
    STAGE_A(1, 0, 1);
    VM2;                                  // tile0 resident; d1.A.t0 in flight
    __builtin_amdgcn_s_barrier();

    const int NITER = K_DIM / 128;        // 16 iterations, 2 K-tiles each
    for (int i = 0; i < NITER; ++i) {
        const int kt1 = 2 * i + 1;
        const int kt2 = (2 * i + 2) & 31; // wrap: redundant harmless loads on last iter
        const int kt3 = (2 * i + 3) & 31;
        PHASE(0, 0, 0, STAGE_B(1, 0, kt1), );
        PHASE(0, 1, 0, STAGE_B(1, 1, kt1), );
        PHASE(0, 0, 1, STAGE_A(1, 1, kt1), );
        PHASE(0, 1, 1, STAGE_A(0, 0, kt2), VM4);
        PHASE(1, 0, 0, { STAGE_B(0, 0, kt2); STAGE_A(0, 1, kt2); }, VM6);
        PHASE(1, 1, 0, STAGE_B(0, 1, kt2), );
        PHASE(1, 0, 1, (void)0, );
        PHASE(1, 1, 1, STAGE_A(1, 0, kt3), VM2);
    }

    // ---- epilogue: drain wrapped prefetch DMAs, then coalesced stores via LDS
    asm volatile("s_waitcnt vmcnt(0)" ::: "memory");
    __syncthreads();

    float* ldsF = (float*)lds;                         // [32][260] fp32, padded
    const int crow  = (lane >> 4) << 2;
    const int rho_w = wr * 16 + crow;                  // + r  (0..31)
    const int col_w = wc * 64 + l15;                   // + nj*16 (0..255)
    const int rho_r = tid >> 4;                        // 0..31
    const int c0    = (tid & 15) << 4;                 // 0..240
    const long gm_r = (long)bm * 256 + (rho_r >> 4) * 128 + (rho_r & 15);  // + mi*16
    const long gn_r = (long)bn * 256 + c0;

    for (int mi = 0; mi < 8; ++mi) {
        #pragma unroll
        for (int nj = 0; nj < 4; ++nj)
            #pragma unroll
            for (int r = 0; r < 4; ++r)
                ldsF[(rho_w + r) * 260 + col_w + nj * 16] = acc[mi][nj][r];
        __syncthreads();
        float4* dst = (float4*)(C + (gm_r + (long)mi * 16) * N_DIM + gn_r);
        const float4* src = (const float4*)(ldsF + rho_r * 260 + c0);
        #pragma unroll
        for (int j = 0; j < 4; ++j) dst[j] = src[j];
        __syncthreads();
    }
}

// ---------------------------------------------------------------- launcher
extern "C" void kernel_launch(void* const* d_in, const int* in_sizes, int n_in,
                              void* d_out, int out_size, void* d_ws, size_t ws_size,
                              hipStream_t stream) {
    const float* x = (const float*)d_in[0];   // (4,2048,2048) fp32
    const float* w = (const float*)d_in[1];   // (8192,2048)  fp32
    float* out = (float*)d_out;               // (4,2048,8192) fp32

    // d_ws: qw bf16 (32 MiB) | xs bf16 (32 MiB) == 64 MiB, no overflow
    char* ws = (char*)d_ws;
    __bf16* qw = (__bf16*)ws;
    __bf16* xs = (__bf16*)(ws + 33554432);

    // reduction scratch in the TAIL of d_out; gemm overwrites it afterwards
    char* tail = (char*)d_out + (size_t)out_size * sizeof(float);
    double* partials = (double*)(tail - 16384);   // 2048 doubles
    float* scalep    = (float*)(tail - 16448);

    absmean1_kernel<<<2048, 256, 0, stream>>>(w, partials);
    absmean2_kernel<<<1, 256, 0, stream>>>(partials, scalep);
    prep_kernel<<<2048, 256, 0, stream>>>(x, w, scalep, xs, qw);
    dim3 grid(32, 32);
    gemm_kernel<<<grid, 512, 0, stream>>>(xs, qw, out);
}

// Round 7
// 595.931 us; speedup vs baseline: 1.0630x; 1.0630x over previous
//
#include <hip/hip_runtime.h>
#include <hip/hip_bf16.h>

// BitNet b1.58 linear: out = scale * (x @ clip(round(w/scale),-1,1)^T)
// scale = 1e-4 + mean(|w|).  M=8192, N=8192, K=2048, fp32 in/out.
// Pipeline: deterministic 2-stage |w| reduction (scratch in d_out tail) ->
// prep (q = bf16 {-1,0,1}, xs = bf16(x*scale)) ->
// 256x256 8-phase bf16 MFMA GEMM (T2 swizzle + T3/T4 counted vmcnt + T5 setprio).
// Round-4 loop schedule (proven 299us/39.6% util/0 conflicts); epilogue via
// MFMA operand swap -> acc regs hold 4 consecutive N -> direct nontemporal
// global_store_dwordx4, no LDS round-trip, no extra barriers.

typedef __bf16 bf16x8 __attribute__((ext_vector_type(8)));
typedef float  f32x4  __attribute__((ext_vector_type(4)));

#define GAS __attribute__((address_space(1)))
#define LAS __attribute__((address_space(3)))

static constexpr int  M_DIM = 8192;
static constexpr int  N_DIM = 8192;
static constexpr int  K_DIM = 2048;
static constexpr long NELEM = 16777216;

// --------------------------------------------- stage 1: per-block |w| sums
__global__ void absmean1_kernel(const float* __restrict__ w, double* __restrict__ partials) {
    double s = 0.0;
    const float4* w4 = (const float4*)w;
    const int n4 = (int)(NELEM / 4);
    for (int i = blockIdx.x * blockDim.x + threadIdx.x; i < n4; i += gridDim.x * blockDim.x) {
        float4 v = w4[i];
        s += (double)fabsf(v.x) + (double)fabsf(v.y) + (double)fabsf(v.z) + (double)fabsf(v.w);
    }
    #pragma unroll
    for (int off = 32; off > 0; off >>= 1) s += __shfl_down(s, off);
    __shared__ double wsum[4];
    if ((threadIdx.x & 63) == 0) wsum[threadIdx.x >> 6] = s;
    __syncthreads();
    if (threadIdx.x == 0) partials[blockIdx.x] = wsum[0] + wsum[1] + wsum[2] + wsum[3];
}

// --------------------------------------------- stage 2: partials -> scale
__global__ void absmean2_kernel(const double* __restrict__ partials, float* __restrict__ scale_out) {
    double s = 0.0;
    #pragma unroll
    for (int j = 0; j < 8; ++j) s += partials[threadIdx.x + 256 * j];
    #pragma unroll
    for (int off = 32; off > 0; off >>= 1) s += __shfl_down(s, off);
    __shared__ double wsum[4];
    if ((threadIdx.x & 63) == 0) wsum[threadIdx.x >> 6] = s;
    __syncthreads();
    if (threadIdx.x == 0) {
        double total = wsum[0] + wsum[1] + wsum[2] + wsum[3];
        scale_out[0] = (float)(1.0e-4 + total * (1.0 / 16777216.0));
    }
}

// ----------------------------- prep: qw = quantized w (bf16), xs = bf16(x*scale)
__global__ void prep_kernel(const float* __restrict__ x, const float* __restrict__ w,
                            const float* __restrict__ scale_in,
                            __bf16* __restrict__ xs, __bf16* __restrict__ qw) {
    const float scale = scale_in[0];
    const int n8 = (int)(NELEM / 8);
    const float4* x4 = (const float4*)x;
    const float4* w4 = (const float4*)w;
    for (int i = blockIdx.x * blockDim.x + threadIdx.x; i < n8; i += gridDim.x * blockDim.x) {
        float4 a0 = x4[2 * i], a1 = x4[2 * i + 1];
        bf16x8 xv;
        xv[0] = (__bf16)(a0.x * scale); xv[1] = (__bf16)(a0.y * scale);
        xv[2] = (__bf16)(a0.z * scale); xv[3] = (__bf16)(a0.w * scale);
        xv[4] = (__bf16)(a1.x * scale); xv[5] = (__bf16)(a1.y * scale);
        xv[6] = (__bf16)(a1.z * scale); xv[7] = (__bf16)(a1.w * scale);
        *(bf16x8*)(xs + 8l * i) = xv;

        float4 b0 = w4[2 * i], b1 = w4[2 * i + 1];
        float wv[8] = {b0.x, b0.y, b0.z, b0.w, b1.x, b1.y, b1.z, b1.w};
        bf16x8 qv;
        #pragma unroll
        for (int e = 0; e < 8; ++e) {
            float r = rintf(wv[e] / scale);
            r = fminf(1.0f, fmaxf(-1.0f, r));
            qv[e] = (__bf16)r;
        }
        *(bf16x8*)(qw + 8l * i) = qv;
    }
}

// ------------------------------------------------------------------ GEMM
// C[m][n] = sum_k A[m][k]*B[n][k].  256x256 tile, BK=64, 512 thr = 8 waves (2Mx4N).
// LDS 128KiB: [dbuf 2][A/B][256 rows][64 cols] bf16, 16B chunks permuted chunk^(row&7)
// (linear dest for global_load_lds, pre-swizzled global source, swizzled ds_read).
// Loop schedule == round-4 (measured 299us, MfmaUtil 39.6%, 0 conflicts):
//   q0:(d0,0,0) stg d1.A.t1(kt1) | q1:(d0,1,0) stg d1.B.h0(kt1) | q2:(d0,0,1) stg d1.B.h1(kt1)
//   q3:(d0,1,1) stg d0.A.t0(kt2)+VM2 | q4:(d1,0,0) stg d0.B.h0(kt2) | q5:(d1,1,0) stg d0.B.h1(kt2)
//   q6:(d1,0,1) stg d0.A.t1(kt2) | q7:(d1,1,1) stg d1.A.t0(kt3)+VM2
// MFMA operands SWAPPED (bg first): D = (C tile)^T per fragment, so per lane
// M row = lane&15 (fixed), N = (lane>>4)*4+reg (4 consecutive) ->
// f32x4 acc stores as one dwordx4 along N.

#define STAGE_A(dd, t, kt) do { \
    _Pragma("unroll") for (int _h = 0; _h < 2; ++_h) { \
        const __bf16* _g = A + (long)(bm * 256 + _h * 128 + (t) * 64 + (tid >> 3)) * K_DIM \
                             + (kt) * 64 + schunk * 8; \
        __builtin_amdgcn_global_load_lds((const GAS unsigned int*)_g, \
            (LAS unsigned int*)(lds + (dd) * 32768 + _h * 8192 + (t) * 4096 + wid * 512), 16, 0, 0); \
    } } while (0)

#define STAGE_B(dd, h, kt) do { \
    _Pragma("unroll") for (int _t = 0; _t < 2; ++_t) { \
        const __bf16* _g = B + (long)(bn * 256 + (h) * 128 + _t * 64 + (tid >> 3)) * K_DIM \
                             + (kt) * 64 + schunk * 8; \
        __builtin_amdgcn_global_load_lds((const GAS unsigned int*)_g, \
            (LAS unsigned int*)(lds + (dd) * 32768 + 16384 + (h) * 8192 + _t * 4096 + wid * 512), 16, 0, 0); \
    } } while (0)

#define VM2 asm volatile("s_waitcnt vmcnt(2)" ::: "memory")

#define PHASE(dd, mq, nq, STG, DOVM) do { \
    bf16x8 af[4][2], bg[2][2]; \
    _Pragma("unroll") for (int mi = 0; mi < 4; ++mi) \
        _Pragma("unroll") for (int kk = 0; kk < 2; ++kk) \
            af[mi][kk] = *(const bf16x8*)(L + (dd) * 65536 \
                + (wr * 128 + (mq) * 64 + mi * 16 + l15) * 128 + (kk ? kb1 : kb0)); \
    _Pragma("unroll") for (int nj = 0; nj < 2; ++nj) \
        _Pragma("unroll") for (int kk = 0; kk < 2; ++kk) \
            bg[nj][kk] = *(const bf16x8*)(L + (dd) * 65536 + 32768 \
                + (wc * 64 + (nq) * 32 + nj * 16 + l15) * 128 + (kk ? kb1 : kb0)); \
    STG; \
    __builtin_amdgcn_s_barrier(); \
    asm volatile("s_waitcnt lgkmcnt(0)" ::: "memory"); \
    __builtin_amdgcn_sched_barrier(0); \
    __builtin_amdgcn_s_setprio(1); \
    _Pragma("unroll") for (int mi = 0; mi < 4; ++mi) \
        _Pragma("unroll") for (int nj = 0; nj < 2; ++nj) \
            _Pragma("unroll") for (int kk = 0; kk < 2; ++kk) \
                acc[(mq) * 4 + mi][(nq) * 2 + nj] = __builtin_amdgcn_mfma_f32_16x16x32_bf16( \
                    bg[nj][kk], af[mi][kk], acc[(mq) * 4 + mi][(nq) * 2 + nj], 0, 0, 0); \
    __builtin_amdgcn_s_setprio(0); \
    DOVM; \
    __builtin_amdgcn_s_barrier(); \
} while (0)

__global__ __launch_bounds__(512, 2) void gemm_kernel(const __bf16* __restrict__ A,
                                                      const __bf16* __restrict__ B,
                                                      float* __restrict__ C) {
    __shared__ __bf16 lds[65536];   // 128 KiB: [d][A/B][256][64]

    const int tid  = threadIdx.x;
    const int lane = tid & 63;
    const int wid  = tid >> 6;       // 0..7
    const int wr   = wid >> 2;       // 0..1 -> M half (128 rows)
    const int wc   = wid & 3;        // 0..3 -> N quarter (64 cols)
    const int l15  = lane & 15;

    // XCD-aware bijective swizzle (nwg = 1024, %8 == 0)
    const int linear = blockIdx.y * gridDim.x + blockIdx.x;
    const int swzid  = (linear & 7) * 128 + (linear >> 3);
    const int bm = swzid >> 5;       // 0..31
    const int bn = swzid & 31;       // 0..31

    // staging: lane covers LDS row tid>>3, chunk tid&7 of an 8KB inst-region;
    // global source chunk pre-swizzled so LDS[row][c] = G[row][c^(row&7)]
    const int schunk = (tid & 7) ^ ((tid >> 3) & 7);

    // fragment-read byte offsets within a 128B row (matching swizzle)
    const int swz = (lane & 7) << 4;
    const int khi = ((lane >> 4) & 3) << 4;
    const int kb0 = khi ^ swz;
    const int kb1 = (khi | 64) ^ swz;
    const char* L = (const char*)lds;

    f32x4 acc[8][4];
    #pragma unroll
    for (int i = 0; i < 8; ++i)
        #pragma unroll
        for (int j = 0; j < 4; ++j)
            acc[i][j] = f32x4{0.0f, 0.0f, 0.0f, 0.0f};

    // prologue: tile0 -> dbuf0 (8 loads), d1.A.t0(kt1) (2 loads); drain tile0
    STAGE_A(0, 0, 0);
    STAGE_A(0, 1, 0);
    STAGE_B(0, 0, 0);
    STAGE_B(0, 1, 0);
    STAGE_A(1, 0, 1);
    VM2;                                  // tile0 resident; d1.A.t0 in flight
    __builtin_amdgcn_s_barrier();

    const int NITER = K_DIM / 128;        // 16 iterations, 2 K-tiles each
    for (int i = 0; i < NITER; ++i) {
        const int kt1 = 2 * i + 1;
        const int kt2 = (2 * i + 2) & 31; // wrap: redundant harmless loads on last iter
        const int kt3 = (2 * i + 3) & 31;
        PHASE(0, 0, 0, STAGE_A(1, 1, kt1), );
        PHASE(0, 1, 0, STAGE_B(1, 0, kt1), );
        PHASE(0, 0, 1, STAGE_B(1, 1, kt1), );
        PHASE(0, 1, 1, STAGE_A(0, 0, kt2), VM2);
        PHASE(1, 0, 0, STAGE_B(0, 0, kt2), );
        PHASE(1, 1, 0, STAGE_B(0, 1, kt2), );
        PHASE(1, 0, 1, STAGE_A(0, 1, kt2), );
        PHASE(1, 1, 1, STAGE_A(1, 0, kt3), VM2);
    }

    // ---- epilogue: swapped-operand layout -> 32 direct nontemporal dwordx4.
    // lane: M row = l15 (fixed), N = (lane>>4)*4 + reg (4 consecutive).
    const int nlo = (lane >> 4) << 2;
    #pragma unroll
    for (int mi = 0; mi < 8; ++mi) {
        const long gm = (long)bm * 256 + wr * 128 + mi * 16 + l15;
        #pragma unroll
        for (int nj = 0; nj < 4; ++nj) {
            const long gn = (long)bn * 256 + wc * 64 + nj * 16 + nlo;
            __builtin_nontemporal_store(acc[mi][nj], (f32x4*)(C + gm * N_DIM + gn));
        }
    }
}

// ---------------------------------------------------------------- launcher
extern "C" void kernel_launch(void* const* d_in, const int* in_sizes, int n_in,
                              void* d_out, int out_size, void* d_ws, size_t ws_size,
                              hipStream_t stream) {
    const float* x = (const float*)d_in[0];   // (4,2048,2048) fp32
    const float* w = (const float*)d_in[1];   // (8192,2048)  fp32
    float* out = (float*)d_out;               // (4,2048,8192) fp32

    // d_ws: qw bf16 (32 MiB) | xs bf16 (32 MiB) == 64 MiB, no overflow
    char* ws = (char*)d_ws;
    __bf16* qw = (__bf16*)ws;
    __bf16* xs = (__bf16*)(ws + 33554432);

    // reduction scratch in the TAIL of d_out; gemm overwrites it afterwards
    char* tail = (char*)d_out + (size_t)out_size * sizeof(float);
    double* partials = (double*)(tail - 16384);   // 2048 doubles
    float* scalep    = (float*)(tail - 16448);

    absmean1_kernel<<<2048, 256, 0, stream>>>(w, partials);
    absmean2_kernel<<<1, 256, 0, stream>>>(partials, scalep);
    prep_kernel<<<2048, 256, 0, stream>>>(x, w, scalep, xs, qw);
    dim3 grid(32, 32);
    gemm_kernel<<<grid, 512, 0, stream>>>(xs, qw, out);
}